// Round 8
// baseline (139.186 us; speedup 1.0000x reference)
//
#include <hip/hip_runtime.h>
#include <cstddef>

#define TT 16384
#define NFRAMES 513
#define NFP 520                 // frames per batch, padded
#define BNP (8 * NFP)           // 4160 = 65 * 64
#define PI32 0.09817477042468103870f   // pi/32

typedef unsigned int u32;
typedef unsigned short u16;
typedef __attribute__((ext_vector_type(8))) short bf16x8;
typedef __attribute__((ext_vector_type(4))) float f32x4;

// u16-table layout after U
#define TAB_WBF 0                        // [33][64][72]
#define TAB_BM  (33 * 64 * 72)           // [80][72]   (STFT A-operand)
#define TAB_BTA (TAB_BM + 80 * 72)       // [64 j][72]: col<64 iDFT*win*scale,
                                         // col 64 = f=32 real column (a64), 65..71 = 0
#define TAB_TOT (TAB_BTA + 64 * 72)
// f32 tables after that
#define TF_EINV 0                        // 32

__device__ __forceinline__ float b2f(u16 h) {
  union { u32 u; float f; } v; v.u = ((u32)h) << 16; return v.f;
}
__device__ __forceinline__ u16 f2b(float f) {
  union { float f; u32 u; } v; v.f = f;
  const u32 r = v.u + 0x7FFFu + ((v.u >> 16) & 1u);   // RNE
  return (u16)(r >> 16);
}
__device__ __forceinline__ u32 pack2(float a, float b) {
  return (u32)f2b(a) | ((u32)f2b(b) << 16);
}

// ---------------------------------------------------------------------------
// K0: constant tables (R3 version -- R2/R6 showed per-block table recompute
// regresses; L2 broadcast table reads are ~free).
// ---------------------------------------------------------------------------
__global__ __launch_bounds__(256) void k0_tables(const float* __restrict__ W,
                                                 u16* __restrict__ t16,
                                                 float* __restrict__ tf) {
  const int b = blockIdx.x, tid = threadIdx.x;
  if (b < 33) {
    for (int idx = tid; idx < 64 * 72; idx += 256) {
      const int o = idx / 72, i = idx % 72;
      const float v = (i < 64) ? W[(size_t)(o * 64 + i) * 33 + b] : 0.f;
      t16[TAB_WBF + b * 64 * 72 + idx] = f2b(v);
    }
  } else if (b == 33) {
    for (int idx = tid; idx < 80 * 72; idx += 256) {
      const int fc = idx / 72, j = idx % 72;
      float v = 0.f;
      if (j < 64 && fc < 65) {
        const float wj = 0.5f * (1.0f - cosf((float)j * PI32));
        if (fc < 64) {
          const int f = fc >> 1;
          const float ang = (float)((f * j) & 63) * PI32;
          v = wj * ((fc & 1) ? -sinf(ang) : cosf(ang));
        } else {
          v = (j & 1) ? -wj : wj;   // f=32 real row
        }
      }
      t16[TAB_BM + idx] = f2b(v);
    }
  } else {   // b == 34
    for (int idx = tid; idx < 64 * 72; idx += 256) {
      const int j = idx / 72, cf = idx % 72;
      float v = 0.f;
      if (cf < 65) {                       // cf=64: f=32, even -> cos branch
        const int f = cf >> 1;
        const float wj = 0.5f * (1.0f - cosf((float)j * PI32));
        const float sc = ((f == 0) || (f == 32)) ? 0.015625f : 0.03125f;
        const float ang = (float)((f * j) & 63) * PI32;
        v = wj * sc * ((cf & 1) ? -sinf(ang) : cosf(ang));
      }
      t16[TAB_BTA + idx] = f2b(v);
    }
    if (tid < 32) {
      const float c = cosf((float)tid * PI32);
      tf[TF_EINV + tid] = 2.0f / (1.0f + c * c);
    }
  }
}

// ---------------------------------------------------------------------------
// K1: STFT via MFMA, software-pipelined over 2 batches per block (R7 version,
// unchanged -- verified -4.7us).
// ---------------------------------------------------------------------------
__global__ __launch_bounds__(256) void k1_stft(const float* __restrict__ x,
                                               const u16* __restrict__ t16,
                                               u16* __restrict__ U) {
  const int tile = blockIdx.x;   // 0..8 (8 == last-frame special path)
  const int ch   = blockIdx.y;
  const int bz   = blockIdx.z;   // 0..3 -> batches bz and bz+4
  const int tid = threadIdx.x;
  __shared__ __align__(16) u16 Bm[80 * 72];
  __shared__ __align__(16) u16 Awt[2][64 * 72];  // [buf][fl][j]
  __shared__ __align__(16) u16 Cs[66 * 72];      // [fc][fl] output repack
  __shared__ float xef[2][64];

  for (int k = tid; k < 720; k += 256)
    ((uint4*)Bm)[k] = ((const uint4*)(t16 + TAB_BM))[k];

  if (tile == 8) {               // frame 512, both batches
    if (tid < 128) {
      const int c = tid >> 6, j = tid & 63;
      const int t = (j < 32) ? (16352 + j) : (16414 - j);
      xef[c][j] = x[(size_t)((bz + 4 * c) * 64 + ch) * TT + t];
    }
    __syncthreads();
    for (int id = tid; id < 132; id += 256) {
      const int c = id / 66, fc = id % 66;
      float s = 0.f;
#pragma unroll 8
      for (int j = 0; j < 64; ++j)
        s = fmaf(xef[c][j], b2f(Bm[fc * 72 + j]), s);
      U[(size_t)(fc * 64 + ch) * BNP + (bz + 4 * c) * NFP + 512] = f2b(s);
    }
    return;
  }

  const int F0 = tile * 64;
  const int wave = tid >> 6, lane = tid & 63;
  const int n = lane & 15, quad = lane >> 4;

  auto issue = [&](const float* xb, float4* v, float& rf) {
    if (tile == 0) {
      if (tid < 32) rf = xb[32 - tid];
      v[0] = *(const float4*)(xb + 4 * (8 + tid) - 32);
      v[1] = *(const float4*)(xb + 4 * (264 + tid) - 32);
    } else {
      const float* src = xb + 32 * F0 - 32;
      v[0] = *(const float4*)(src + 4 * tid);
      v[1] = *(const float4*)(src + 4 * (tid + 256));
      if (tid < 8) v[2] = *(const float4*)(src + 4 * (tid + 512));
    }
  };
  auto writeA = [&](u16* Aw, const float4* v, float rf) {
    if (tile == 0) {
      if (tid < 32) Aw[tid] = f2b(rf);      // left reflect, frame 0
#pragma unroll
      for (int q = 0; q < 2; ++q) {
        const int c = 8 + tid + 256 * q;
        const uint2 pk = make_uint2(pack2(v[q].x, v[q].y), pack2(v[q].z, v[q].w));
        const int flb = c >> 3, jj = 4 * (c & 7);
        if (flb < 64) *(uint2*)&Aw[flb * 72 + jj] = pk;
        *(uint2*)&Aw[(flb - 1) * 72 + 32 + jj] = pk;
      }
    } else {
#pragma unroll
      for (int q = 0; q < 3; ++q) {
        if (q == 2 && tid >= 8) continue;
        const int c = tid + 256 * q;
        const uint2 pk = make_uint2(pack2(v[q].x, v[q].y), pack2(v[q].z, v[q].w));
        const int flb = c >> 3, jj = 4 * (c & 7);
        if (flb < 64) *(uint2*)&Aw[flb * 72 + jj] = pk;
        if (flb >= 1) *(uint2*)&Aw[(flb - 1) * 72 + 32 + jj] = pk;
      }
    }
  };

  bf16x8 afm[2], afx[2];
  bf16x8 bfr[4][2];
  auto frag = [&](const u16* Aw) {
#pragma unroll
    for (int nt = 0; nt < 4; ++nt)
#pragma unroll
      for (int ks = 0; ks < 2; ++ks)
        bfr[nt][ks] = *(const bf16x8*)&Aw[(nt * 16 + n) * 72 + ks * 32 + quad * 8];
  };
  auto computeCs = [&]() {
    const int npass = (wave == 0) ? 2 : 1;
    for (int pass = 0; pass < npass; ++pass) {
      const bf16x8* af = pass ? afx : afm;
      const int mt = pass ? 4 : wave;
      f32x4 acc[4];
#pragma unroll
      for (int nt = 0; nt < 4; ++nt) acc[nt] = (f32x4){0.f, 0.f, 0.f, 0.f};
#pragma unroll
      for (int ks = 0; ks < 2; ++ks)
#pragma unroll
        for (int nt = 0; nt < 4; ++nt)
          acc[nt] = __builtin_amdgcn_mfma_f32_16x16x32_bf16(af[ks], bfr[nt][ks],
                                                            acc[nt], 0, 0, 0);
#pragma unroll
      for (int nt = 0; nt < 4; ++nt) {
        const int fl = nt * 16 + n;
#pragma unroll
        for (int r = 0; r < 4; ++r) {
          const int fc = mt * 16 + quad * 4 + r;
          if (fc < 66) Cs[fc * 72 + fl] = f2b(acc[nt][r]);
        }
      }
    }
  };
  auto copyout = [&](int beff) {
    const int bnb = beff * NFP + F0;
    for (int k = tid; k < 528; k += 256) {
      const int fc = k >> 3, part = k & 7;
      *(uint4*)(U + (size_t)(fc * 64 + ch) * BNP + bnb + part * 8) =
          *(const uint4*)&Cs[fc * 72 + part * 8];
    }
  };

  const float* xbA = x + (size_t)(bz * 64 + ch) * TT;
  const float* xbB = x + (size_t)((bz + 4) * 64 + ch) * TT;

  float4 va[3] = {}; float ra = 0.f;
  issue(xbA, va, ra);
  writeA(Awt[0], va, ra);
  __syncthreads();                       // bar1: Bm + Awt0 ready

#pragma unroll
  for (int ks = 0; ks < 2; ++ks)
    afm[ks] = *(const bf16x8*)&Bm[(wave * 16 + n) * 72 + ks * 32 + quad * 8];
  if (wave == 0) {
#pragma unroll
    for (int ks = 0; ks < 2; ++ks)
      afx[ks] = *(const bf16x8*)&Bm[(64 + n) * 72 + ks * 32 + quad * 8];
  }

  frag(Awt[0]);
  float4 vb[3] = {}; float rb = 0.f;
  issue(xbB, vb, rb);                    // batch-1 loads in flight...
  computeCs();                           // ...hidden under batch-0 MFMA+pack
  __syncthreads();                       // bar2: Cs0 ready, frag0 reads done

  copyout(bz);
  writeA(Awt[1], vb, rb);
  __syncthreads();                       // bar3: copyout0 done, Awt1 ready

  frag(Awt[1]);
  computeCs();
  __syncthreads();                       // bar4: Cs1 ready
  copyout(bz + 4);
}

// ---------------------------------------------------------------------------
// K2: channel mix via MFMA, IN PLACE over U (R3/R5 version, unchanged).
// ---------------------------------------------------------------------------
__global__ __launch_bounds__(256) void k2_mix(const u16* __restrict__ t16,
                                              u16* __restrict__ U) {
  const int f   = blockIdx.y;
  const int bn0 = blockIdx.x * 64;
  const int tid = threadIdx.x;
  __shared__ __align__(16) u16 Ut[2 * 64 * 72];   // in: [c][q][i swz]; out: [128 row][72]
  __shared__ __align__(16) u16 Wl[64 * 72];       // [o][i]

  for (int k = tid; k < 576; k += 256)
    ((uint4*)Wl)[k] = ((const uint4*)(t16 + TAB_WBF + f * 64 * 72))[k];

#pragma unroll
  for (int kk = 0; kk < 4; ++kk) {
    const int id = tid + kk * 256;
    const int c = id >> 9, rem = id & 511;
    const int i = rem >> 3, qc = rem & 7;
    const uint4 raw = *(const uint4*)(U + (size_t)((2 * f + c) * 64 + i) * BNP + bn0 + 8 * qc);
    const int col = (((i >> 3) ^ qc) << 3) + (i & 7);
    u16* base = &Ut[c * 4608 + col];
#pragma unroll
    for (int e = 0; e < 8; ++e) {
      const u32 w = ((const u32*)&raw)[e >> 1];
      base[(8 * qc + e) * 72] = (u16)((e & 1) ? (w >> 16) : (w & 0xFFFFu));
    }
  }
  __syncthreads();

  const int wave = tid >> 6, lane = tid & 63;
  const int n = lane & 15, quad = lane >> 4;
  const int mt = wave;

  bf16x8 af[2];
#pragma unroll
  for (int ks = 0; ks < 2; ++ks)
    af[ks] = *(const bf16x8*)&Wl[(mt * 16 + n) * 72 + ks * 32 + quad * 8];

  f32x4 acc[4][2];
#pragma unroll
  for (int nt = 0; nt < 4; ++nt)
#pragma unroll
    for (int c = 0; c < 2; ++c) acc[nt][c] = (f32x4){0.f, 0.f, 0.f, 0.f};

#pragma unroll
  for (int ks = 0; ks < 2; ++ks)
#pragma unroll
    for (int nt = 0; nt < 4; ++nt) {
      const int q = nt * 16 + n;
      const int chunk = (((ks << 2) + quad) ^ ((q >> 3) & 7)) << 3;
#pragma unroll
      for (int c = 0; c < 2; ++c) {
        const bf16x8 bf = *(const bf16x8*)&Ut[c * 4608 + q * 72 + chunk];
        acc[nt][c] = __builtin_amdgcn_mfma_f32_16x16x32_bf16(af[ks], bf,
                                                             acc[nt][c], 0, 0, 0);
      }
    }
  __syncthreads();   // all fragment reads done -- Ut reusable as out-staging

#pragma unroll
  for (int nt = 0; nt < 4; ++nt) {
    const int col = nt * 16 + n;
#pragma unroll
    for (int c = 0; c < 2; ++c)
#pragma unroll
      for (int r = 0; r < 4; ++r) {
        const int o = mt * 16 + quad * 4 + r;
        Ut[(c * 64 + o) * 72 + col] = f2b(acc[nt][c][r]);
      }
  }
  __syncthreads();

  // coalesced copy-out: 128 rows x 64 u16 as uint4
  for (int k = tid; k < 1024; k += 256) {
    const int row = k >> 3, part = k & 7;
    const int c = row >> 6, o = row & 63;
    *(uint4*)(U + (size_t)((2 * f + c) * 64 + o) * BNP + bn0 + part * 8) =
        *(const uint4*)&Ut[row * 72 + part * 8];
  }
}

// ---------------------------------------------------------------------------
// K3: ISTFT via MFMA, K=64 + rank-1 cf=64 term, register OLA -- now
// SOFTWARE-PIPELINED over 2 batches per block (bz, bz+4), same T14 pattern
// as k1: BtA/af/a64v/einv amortized; batch-B Y loads issued before batch-A
// compute, scattered into Yt[1] after it.  Per-batch arithmetic identical.
// LDS ~30 KB (5 blocks/CU); grid z halves (2048 blocks).
// ---------------------------------------------------------------------------
__global__ __launch_bounds__(256, 4) void k3_istft(const u16* __restrict__ Y,
                                                   const u16* __restrict__ t16,
                                                   const float* __restrict__ tf,
                                                   float* __restrict__ out) {
  const int tile = blockIdx.x;   // 0..7
  const int o    = blockIdx.y;
  const int bz   = blockIdx.z;   // 0..3 -> batches bz and bz+4
  const int n0 = tile * 64;
  const int tid = threadIdx.x;
  __shared__ __align__(16) u16 BtA[64 * 72];    // [j][cf]; col 64 = a64
  __shared__ __align__(16) u16 Yt[2][80 * 64];  // [buf][fl][cf], chunk-swizzled
  __shared__ __align__(16) u16 y64[2][72];      // Y row cf=64 per buf
  __shared__ __align__(16) float einv[32];

  for (int k = tid; k < 576; k += 256)          // 64*72/8
    ((uint4*)BtA)[k] = ((const uint4*)(t16 + TAB_BTA))[k];
  if (tid < 32) einv[tid] = tf[TF_EINV + tid];

  const size_t ybA = (size_t)bz * NFP + n0;
  const size_t ybB = (size_t)(bz + 4) * NFP + n0;

  auto issueY = [&](size_t yb, uint4* raw, uint4& r64) {
#pragma unroll
    for (int q = 0; q < 3; ++q) {
      const int id = tid + 256 * q;
      if (q < 2 || id < 576) {                  // 64 cf x 9 fl-octs
        const int cf = id / 9, oct = id % 9;    // oct 8 reads fl 64..71 (pad ok)
        raw[q] = *(const uint4*)(Y + (size_t)(cf * 64 + o) * BNP + yb + oct * 8);
      }
    }
    if (tid < 9)
      r64 = *(const uint4*)(Y + (size_t)(64 * 64 + o) * BNP + yb + tid * 8);
  };
  auto scatterY = [&](int buf, const uint4* raw, const uint4& r64) {
#pragma unroll
    for (int q = 0; q < 3; ++q) {
      const int id = tid + 256 * q;
      if (q < 2 || id < 576) {
        const int cf = id / 9, oct = id % 9;
        const u16* s = (const u16*)&raw[q];
#pragma unroll
        for (int e = 0; e < 8; ++e) {
          const int row = oct * 8 + e;
          const int sw = (row ^ (row >> 3)) & 7;
          Yt[buf][row * 64 + ((((cf >> 3) ^ sw) << 3) | (cf & 7))] = s[e];
        }
      }
    }
    if (tid < 9) *(uint4*)&y64[buf][tid * 8] = r64;
  };

  const int wave = tid >> 6, lane = tid & 63;
  const int n = lane & 15, quad = lane >> 4;

  uint4 rawA[3] = {}; uint4 r64A = {};
  issueY(ybA, rawA, r64A);
  scatterY(0, rawA, r64A);
  uint4 rawB[3] = {}; uint4 r64B = {};
  issueY(ybB, rawB, r64B);               // B loads in flight across A compute
  __syncthreads();                       // bar1: BtA + Yt[0] + einv ready

  // A-row remap: A row m of this wave holds BtA row j(m) = wave*8+(m&7)+(m>>3)*32
  const int jrowA = wave * 8 + (n & 7) + (n >> 3) * 32;
  bf16x8 af[2];
#pragma unroll
  for (int ks = 0; ks < 2; ++ks)
    af[ks] = *(const bf16x8*)&BtA[jrowA * 72 + ks * 32 + quad * 8];

  float a64v[4];
#pragma unroll
  for (int r = 0; r < 4; ++r) {
    const int c = quad * 4 + r;
    const int j = wave * 8 + (c & 7) + (c >> 3) * 32;
    a64v[r] = b2f(BtA[j * 72 + 64]);
  }

  const int srcl = (((n + 15) & 15) | ((2 | (quad & 1)) << 4)) << 2;
  const float4 ev = *(const float4*)&einv[wave * 8 + (quad & 1) * 4];

  auto computeOLA = [&](int buf, int beff) {
    f32x4 acc[5];
#pragma unroll
    for (int nt = 0; nt < 5; ++nt) acc[nt] = (f32x4){0.f, 0.f, 0.f, 0.f};
#pragma unroll
    for (int nt = 0; nt < 5; ++nt) {
      const int row = nt * 16 + n;
      const int sw = (row ^ (row >> 3)) & 7;
      const u16* yrow = &Yt[buf][row * 64];
#pragma unroll
      for (int ks = 0; ks < 2; ++ks) {
        const bf16x8 bf = *(const bf16x8*)&yrow[((ks * 4 + quad) ^ sw) << 3];
        acc[nt] = __builtin_amdgcn_mfma_f32_16x16x32_bf16(af[ks], bf, acc[nt], 0, 0, 0);
      }
    }
    // register OLA: hi (quads 2,3) -> lo (quads 0,1), lane n-1 -> n
    float* pob = out + (size_t)(beff * 64 + o) * TT + 32 * n0 + wave * 8 + (quad & 1) * 4;
    float hiPrev[4] = {0.f, 0.f, 0.f, 0.f};
#pragma unroll
    for (int nt = 0; nt < 5; ++nt) {
      const int fl = nt * 16 + n;
      if (nt < 4 || n == 0) {                  // rank-1 cf=64 term (fl <= 64)
        const float yv = b2f(y64[buf][fl]);
#pragma unroll
        for (int r = 0; r < 4; ++r) acc[nt][r] = fmaf(yv, a64v[r], acc[nt][r]);
      }
      float cur[4];
#pragma unroll
      for (int r = 0; r < 4; ++r)
        cur[r] = __int_as_float(
            __builtin_amdgcn_ds_bpermute(srcl, __float_as_int(acc[nt][r])));
      if (quad < 2) {
        const bool valid = (nt < 4) ? (fl > 0) : (n == 0);
        if (valid) {
          float v[4];
#pragma unroll
          for (int r = 0; r < 4; ++r)
            v[r] = (acc[nt][r] + ((n == 0) ? hiPrev[r] : cur[r])) * ev[r];
          *(float4*)(pob + (fl - 1) * 32) = make_float4(v[0], v[1], v[2], v[3]);
        }
      }
#pragma unroll
      for (int r = 0; r < 4; ++r) hiPrev[r] = cur[r];
    }
  };

  computeOLA(0, bz);                     // B loads land during this
  scatterY(1, rawB, r64B);
  __syncthreads();                       // bar2: Yt[1] ready
  computeOLA(1, bz + 4);
}

// ---------------------------------------------------------------------------
extern "C" void kernel_launch(void* const* d_in, const int* in_sizes, int n_in,
                              void* d_out, int out_size, void* d_ws, size_t ws_size,
                              hipStream_t stream) {
  const float* x  = (const float*)d_in[0];   // [8,64,16384]
  const float* wt = (const float*)d_in[1];   // [64,64,33]
  float* out = (float*)d_out;                // [8,64,16384]
  u16* U = (u16*)d_ws;                                        // 35.1 MB bf16
  u16* t16 = (u16*)((char*)d_ws + (size_t)66 * 64 * BNP * 2); // bf16 tables
  float* tf = (float*)(t16 + TAB_TOT);                        // fp32 tables

  dim3 blk(256);
  k0_tables<<<dim3(35),       blk, 0, stream>>>(wt, t16, tf);
  k1_stft  <<<dim3(9, 64, 4), blk, 0, stream>>>(x, t16, U);   // 2 batches/block
  k2_mix   <<<dim3(65, 33),   blk, 0, stream>>>(t16, U);
  k3_istft <<<dim3(8, 64, 4), blk, 0, stream>>>(U, t16, tf, out);  // 2 batches/block
}

// Round 9
// 134.590 us; speedup vs baseline: 1.0341x; 1.0341x over previous
//
#include <hip/hip_runtime.h>
#include <cstddef>

#define TT 16384
#define NFRAMES 513
#define NFP 520                 // frames per batch, padded
#define BNP (8 * NFP)           // 4160 = 65 * 64
#define PI32 0.09817477042468103870f   // pi/32

typedef unsigned int u32;
typedef unsigned short u16;
typedef __attribute__((ext_vector_type(8))) short bf16x8;
typedef __attribute__((ext_vector_type(4))) float f32x4;

// u16-table layout after U
#define TAB_WBF 0                        // [33][64][72]
#define TAB_BM  (33 * 64 * 72)           // [80][72]   (STFT A-operand)
#define TAB_BTA (TAB_BM + 80 * 72)       // [64 j][72]: col<64 iDFT*win*scale,
                                         // col 64 = f=32 real column (a64), 65..71 = 0
#define TAB_TOT (TAB_BTA + 64 * 72)
// f32 tables after that
#define TF_EINV 0                        // 32

__device__ __forceinline__ float b2f(u16 h) {
  union { u32 u; float f; } v; v.u = ((u32)h) << 16; return v.f;
}
__device__ __forceinline__ u16 f2b(float f) {
  union { float f; u32 u; } v; v.f = f;
  const u32 r = v.u + 0x7FFFu + ((v.u >> 16) & 1u);   // RNE
  return (u16)(r >> 16);
}
__device__ __forceinline__ u32 pack2(float a, float b) {
  return (u32)f2b(a) | ((u32)f2b(b) << 16);
}

// ---------------------------------------------------------------------------
// K0: constant tables (R2/R6 showed per-block table recompute regresses;
// L2 broadcast table reads are ~free).
// ---------------------------------------------------------------------------
__global__ __launch_bounds__(256) void k0_tables(const float* __restrict__ W,
                                                 u16* __restrict__ t16,
                                                 float* __restrict__ tf) {
  const int b = blockIdx.x, tid = threadIdx.x;
  if (b < 33) {
    for (int idx = tid; idx < 64 * 72; idx += 256) {
      const int o = idx / 72, i = idx % 72;
      const float v = (i < 64) ? W[(size_t)(o * 64 + i) * 33 + b] : 0.f;
      t16[TAB_WBF + b * 64 * 72 + idx] = f2b(v);
    }
  } else if (b == 33) {
    for (int idx = tid; idx < 80 * 72; idx += 256) {
      const int fc = idx / 72, j = idx % 72;
      float v = 0.f;
      if (j < 64 && fc < 65) {
        const float wj = 0.5f * (1.0f - cosf((float)j * PI32));
        if (fc < 64) {
          const int f = fc >> 1;
          const float ang = (float)((f * j) & 63) * PI32;
          v = wj * ((fc & 1) ? -sinf(ang) : cosf(ang));
        } else {
          v = (j & 1) ? -wj : wj;   // f=32 real row
        }
      }
      t16[TAB_BM + idx] = f2b(v);
    }
  } else {   // b == 34
    for (int idx = tid; idx < 64 * 72; idx += 256) {
      const int j = idx / 72, cf = idx % 72;
      float v = 0.f;
      if (cf < 65) {                       // cf=64: f=32, even -> cos branch
        const int f = cf >> 1;
        const float wj = 0.5f * (1.0f - cosf((float)j * PI32));
        const float sc = ((f == 0) || (f == 32)) ? 0.015625f : 0.03125f;
        const float ang = (float)((f * j) & 63) * PI32;
        v = wj * sc * ((cf & 1) ? -sinf(ang) : cosf(ang));
      }
      t16[TAB_BTA + idx] = f2b(v);
    }
    if (tid < 32) {
      const float c = cosf((float)tid * PI32);
      tf[TF_EINV + tid] = 2.0f / (1.0f + c * c);
    }
  }
}

// ---------------------------------------------------------------------------
// K1: STFT via MFMA, software-pipelined over 2 batches per block (R7 version,
// verified -4.7us: x loads are HBM-latency, overlap pays).
// ---------------------------------------------------------------------------
__global__ __launch_bounds__(256) void k1_stft(const float* __restrict__ x,
                                               const u16* __restrict__ t16,
                                               u16* __restrict__ U) {
  const int tile = blockIdx.x;   // 0..8 (8 == last-frame special path)
  const int ch   = blockIdx.y;
  const int bz   = blockIdx.z;   // 0..3 -> batches bz and bz+4
  const int tid = threadIdx.x;
  __shared__ __align__(16) u16 Bm[80 * 72];
  __shared__ __align__(16) u16 Awt[2][64 * 72];  // [buf][fl][j]
  __shared__ __align__(16) u16 Cs[66 * 72];      // [fc][fl] output repack
  __shared__ float xef[2][64];

  for (int k = tid; k < 720; k += 256)
    ((uint4*)Bm)[k] = ((const uint4*)(t16 + TAB_BM))[k];

  if (tile == 8) {               // frame 512, both batches
    if (tid < 128) {
      const int c = tid >> 6, j = tid & 63;
      const int t = (j < 32) ? (16352 + j) : (16414 - j);
      xef[c][j] = x[(size_t)((bz + 4 * c) * 64 + ch) * TT + t];
    }
    __syncthreads();
    for (int id = tid; id < 132; id += 256) {
      const int c = id / 66, fc = id % 66;
      float s = 0.f;
#pragma unroll 8
      for (int j = 0; j < 64; ++j)
        s = fmaf(xef[c][j], b2f(Bm[fc * 72 + j]), s);
      U[(size_t)(fc * 64 + ch) * BNP + (bz + 4 * c) * NFP + 512] = f2b(s);
    }
    return;
  }

  const int F0 = tile * 64;
  const int wave = tid >> 6, lane = tid & 63;
  const int n = lane & 15, quad = lane >> 4;

  auto issue = [&](const float* xb, float4* v, float& rf) {
    if (tile == 0) {
      if (tid < 32) rf = xb[32 - tid];
      v[0] = *(const float4*)(xb + 4 * (8 + tid) - 32);
      v[1] = *(const float4*)(xb + 4 * (264 + tid) - 32);
    } else {
      const float* src = xb + 32 * F0 - 32;
      v[0] = *(const float4*)(src + 4 * tid);
      v[1] = *(const float4*)(src + 4 * (tid + 256));
      if (tid < 8) v[2] = *(const float4*)(src + 4 * (tid + 512));
    }
  };
  auto writeA = [&](u16* Aw, const float4* v, float rf) {
    if (tile == 0) {
      if (tid < 32) Aw[tid] = f2b(rf);      // left reflect, frame 0
#pragma unroll
      for (int q = 0; q < 2; ++q) {
        const int c = 8 + tid + 256 * q;
        const uint2 pk = make_uint2(pack2(v[q].x, v[q].y), pack2(v[q].z, v[q].w));
        const int flb = c >> 3, jj = 4 * (c & 7);
        if (flb < 64) *(uint2*)&Aw[flb * 72 + jj] = pk;
        *(uint2*)&Aw[(flb - 1) * 72 + 32 + jj] = pk;
      }
    } else {
#pragma unroll
      for (int q = 0; q < 3; ++q) {
        if (q == 2 && tid >= 8) continue;
        const int c = tid + 256 * q;
        const uint2 pk = make_uint2(pack2(v[q].x, v[q].y), pack2(v[q].z, v[q].w));
        const int flb = c >> 3, jj = 4 * (c & 7);
        if (flb < 64) *(uint2*)&Aw[flb * 72 + jj] = pk;
        if (flb >= 1) *(uint2*)&Aw[(flb - 1) * 72 + 32 + jj] = pk;
      }
    }
  };

  bf16x8 afm[2], afx[2];
  bf16x8 bfr[4][2];
  auto frag = [&](const u16* Aw) {
#pragma unroll
    for (int nt = 0; nt < 4; ++nt)
#pragma unroll
      for (int ks = 0; ks < 2; ++ks)
        bfr[nt][ks] = *(const bf16x8*)&Aw[(nt * 16 + n) * 72 + ks * 32 + quad * 8];
  };
  auto computeCs = [&]() {
    const int npass = (wave == 0) ? 2 : 1;
    for (int pass = 0; pass < npass; ++pass) {
      const bf16x8* af = pass ? afx : afm;
      const int mt = pass ? 4 : wave;
      f32x4 acc[4];
#pragma unroll
      for (int nt = 0; nt < 4; ++nt) acc[nt] = (f32x4){0.f, 0.f, 0.f, 0.f};
#pragma unroll
      for (int ks = 0; ks < 2; ++ks)
#pragma unroll
        for (int nt = 0; nt < 4; ++nt)
          acc[nt] = __builtin_amdgcn_mfma_f32_16x16x32_bf16(af[ks], bfr[nt][ks],
                                                            acc[nt], 0, 0, 0);
#pragma unroll
      for (int nt = 0; nt < 4; ++nt) {
        const int fl = nt * 16 + n;
#pragma unroll
        for (int r = 0; r < 4; ++r) {
          const int fc = mt * 16 + quad * 4 + r;
          if (fc < 66) Cs[fc * 72 + fl] = f2b(acc[nt][r]);
        }
      }
    }
  };
  auto copyout = [&](int beff) {
    const int bnb = beff * NFP + F0;
    for (int k = tid; k < 528; k += 256) {
      const int fc = k >> 3, part = k & 7;
      *(uint4*)(U + (size_t)(fc * 64 + ch) * BNP + bnb + part * 8) =
          *(const uint4*)&Cs[fc * 72 + part * 8];
    }
  };

  const float* xbA = x + (size_t)(bz * 64 + ch) * TT;
  const float* xbB = x + (size_t)((bz + 4) * 64 + ch) * TT;

  float4 va[3] = {}; float ra = 0.f;
  issue(xbA, va, ra);
  writeA(Awt[0], va, ra);
  __syncthreads();                       // bar1: Bm + Awt0 ready

#pragma unroll
  for (int ks = 0; ks < 2; ++ks)
    afm[ks] = *(const bf16x8*)&Bm[(wave * 16 + n) * 72 + ks * 32 + quad * 8];
  if (wave == 0) {
#pragma unroll
    for (int ks = 0; ks < 2; ++ks)
      afx[ks] = *(const bf16x8*)&Bm[(64 + n) * 72 + ks * 32 + quad * 8];
  }

  frag(Awt[0]);
  float4 vb[3] = {}; float rb = 0.f;
  issue(xbB, vb, rb);                    // batch-1 loads in flight...
  computeCs();                           // ...hidden under batch-0 MFMA+pack
  __syncthreads();                       // bar2: Cs0 ready, frag0 reads done

  copyout(bz);
  writeA(Awt[1], vb, rb);
  __syncthreads();                       // bar3: copyout0 done, Awt1 ready

  frag(Awt[1]);
  computeCs();
  __syncthreads();                       // bar4: Cs1 ready
  copyout(bz + 4);
}

// ---------------------------------------------------------------------------
// K2: channel mix via MFMA, IN PLACE over U.  Staging now pairs adjacent
// input channels (i0 even, i0+1): one u32 LDS write carries both -> LDS
// write instructions halve (8192->4096/block) and the write pattern is
// bank-conflict-free (bank = 36e + 4((ip>>2)^qc) + (ip&3), a permutation
// per half-wave).  Data bits, swizzle, and read path identical.
// ---------------------------------------------------------------------------
__global__ __launch_bounds__(256) void k2_mix(const u16* __restrict__ t16,
                                              u16* __restrict__ U) {
  const int f   = blockIdx.y;
  const int bn0 = blockIdx.x * 64;
  const int tid = threadIdx.x;
  __shared__ __align__(16) u16 Ut[2 * 64 * 72];   // in: [c][q][i swz]; out: [128 row][72]
  __shared__ __align__(16) u16 Wl[64 * 72];       // [o][i]

  for (int k = tid; k < 576; k += 256)
    ((uint4*)Wl)[k] = ((const uint4*)(t16 + TAB_WBF + f * 64 * 72))[k];

#pragma unroll
  for (int kk = 0; kk < 2; ++kk) {
    const int id = tid + kk * 256;          // 0..511
    const int c = id >> 8, rem = id & 255;
    const int ip = rem >> 3, qc = rem & 7;  // channel pair i0=2*ip, i0+1
    const int i0 = 2 * ip;
    const size_t rowbase = (size_t)((2 * f + c) * 64 + i0) * BNP + bn0 + 8 * qc;
    const uint4 r0 = *(const uint4*)(U + rowbase);
    const uint4 r1 = *(const uint4*)(U + rowbase + BNP);
    const int col = (((i0 >> 3) ^ qc) << 3) + (i0 & 7);   // even -> u32 aligned
    u32* base = (u32*)&Ut[c * 4608 + col];
#pragma unroll
    for (int e = 0; e < 8; ++e) {
      const u32 w0 = ((const u32*)&r0)[e >> 1];
      const u32 w1 = ((const u32*)&r1)[e >> 1];
      const u32 pk = (e & 1) ? ((w0 >> 16) | (w1 & 0xFFFF0000u))
                             : ((w0 & 0xFFFFu) | (w1 << 16));
      base[(8 * qc + e) * 36] = pk;         // row stride 72 u16 = 36 u32
    }
  }
  __syncthreads();

  const int wave = tid >> 6, lane = tid & 63;
  const int n = lane & 15, quad = lane >> 4;
  const int mt = wave;

  bf16x8 af[2];
#pragma unroll
  for (int ks = 0; ks < 2; ++ks)
    af[ks] = *(const bf16x8*)&Wl[(mt * 16 + n) * 72 + ks * 32 + quad * 8];

  f32x4 acc[4][2];
#pragma unroll
  for (int nt = 0; nt < 4; ++nt)
#pragma unroll
    for (int c = 0; c < 2; ++c) acc[nt][c] = (f32x4){0.f, 0.f, 0.f, 0.f};

#pragma unroll
  for (int ks = 0; ks < 2; ++ks)
#pragma unroll
    for (int nt = 0; nt < 4; ++nt) {
      const int q = nt * 16 + n;
      const int chunk = (((ks << 2) + quad) ^ ((q >> 3) & 7)) << 3;
#pragma unroll
      for (int c = 0; c < 2; ++c) {
        const bf16x8 bf = *(const bf16x8*)&Ut[c * 4608 + q * 72 + chunk];
        acc[nt][c] = __builtin_amdgcn_mfma_f32_16x16x32_bf16(af[ks], bf,
                                                             acc[nt][c], 0, 0, 0);
      }
    }
  __syncthreads();   // all fragment reads done -- Ut reusable as out-staging

#pragma unroll
  for (int nt = 0; nt < 4; ++nt) {
    const int col = nt * 16 + n;
#pragma unroll
    for (int c = 0; c < 2; ++c)
#pragma unroll
      for (int r = 0; r < 4; ++r) {
        const int o = mt * 16 + quad * 4 + r;
        Ut[(c * 64 + o) * 72 + col] = f2b(acc[nt][c][r]);
      }
  }
  __syncthreads();

  // coalesced copy-out: 128 rows x 64 u16 as uint4
  for (int k = tid; k < 1024; k += 256) {
    const int row = k >> 3, part = k & 7;
    const int c = row >> 6, o = row & 63;
    *(uint4*)(U + (size_t)((2 * f + c) * 64 + o) * BNP + bn0 + part * 8) =
        *(const uint4*)&Ut[row * 72 + part * 8];
  }
}

// ---------------------------------------------------------------------------
// K3: ISTFT via MFMA, K=64 + rank-1 cf=64 term, register OLA (R5 version,
// reverted -- R8 showed 2-batch pipelining regresses here: Y loads are
// L2/L3-resident and already TLP-hidden; pipelining only cost occupancy).
// ---------------------------------------------------------------------------
__global__ __launch_bounds__(256, 6) void k3_istft(const u16* __restrict__ Y,
                                                   const u16* __restrict__ t16,
                                                   const float* __restrict__ tf,
                                                   float* __restrict__ out) {
  const int tile = blockIdx.x;   // 0..7
  const int o    = blockIdx.y;
  const int b    = blockIdx.z;
  const int n0 = tile * 64;
  const int tid = threadIdx.x;
  __shared__ __align__(16) u16 BtA[64 * 72];   // [j][cf]; col 64 = a64
  __shared__ __align__(16) u16 Yt[80 * 64];    // [fl][cf], chunk-swizzled
  __shared__ __align__(16) u16 y64[72];        // Y row cf=64
  __shared__ __align__(16) float einv[32];

  for (int k = tid; k < 576; k += 256)         // 64*72/8
    ((uint4*)BtA)[k] = ((const uint4*)(t16 + TAB_BTA))[k];

  const size_t ybase = (size_t)b * NFP + n0;
  for (int id = tid; id < 576; id += 256) {    // 64 cf x 9 fl-octs
    const int cf = id / 9, oct = id % 9;       // oct 8 reads fl 64..71 (pad ok)
    const uint4 raw = *(const uint4*)(Y + (size_t)(cf * 64 + o) * BNP + ybase + oct * 8);
    const u16* s = (const u16*)&raw;
#pragma unroll
    for (int e = 0; e < 8; ++e) {
      const int row = oct * 8 + e;
      const int sw = (row ^ (row >> 3)) & 7;
      Yt[row * 64 + ((((cf >> 3) ^ sw) << 3) | (cf & 7))] = s[e];
    }
  }
  if (tid < 9)
    *(uint4*)&y64[tid * 8] =
        *(const uint4*)(Y + (size_t)(64 * 64 + o) * BNP + ybase + tid * 8);
  if (tid < 32) einv[tid] = tf[TF_EINV + tid];
  __syncthreads();

  const int wave = tid >> 6, lane = tid & 63;
  const int n = lane & 15, quad = lane >> 4;

  // A-row remap: A row m of this wave holds BtA row j(m) = wave*8+(m&7)+(m>>3)*32
  const int jrowA = wave * 8 + (n & 7) + (n >> 3) * 32;
  bf16x8 af[2];
#pragma unroll
  for (int ks = 0; ks < 2; ++ks)
    af[ks] = *(const bf16x8*)&BtA[jrowA * 72 + ks * 32 + quad * 8];

  float a64v[4];
#pragma unroll
  for (int r = 0; r < 4; ++r) {
    const int c = quad * 4 + r;
    const int j = wave * 8 + (c & 7) + (c >> 3) * 32;
    a64v[r] = b2f(BtA[j * 72 + 64]);
  }

  f32x4 acc[5];
#pragma unroll
  for (int nt = 0; nt < 5; ++nt) acc[nt] = (f32x4){0.f, 0.f, 0.f, 0.f};
#pragma unroll
  for (int nt = 0; nt < 5; ++nt) {
    const int row = nt * 16 + n;
    const int sw = (row ^ (row >> 3)) & 7;
    const u16* yrow = &Yt[row * 64];
#pragma unroll
    for (int ks = 0; ks < 2; ++ks) {
      const bf16x8 bf = *(const bf16x8*)&yrow[((ks * 4 + quad) ^ sw) << 3];
      acc[nt] = __builtin_amdgcn_mfma_f32_16x16x32_bf16(af[ks], bf, acc[nt], 0, 0, 0);
    }
  }

  // register OLA: hi (quads 2,3) -> lo (quads 0,1), lane n-1 -> n
  const int srcl = (((n + 15) & 15) | ((2 | (quad & 1)) << 4)) << 2;
  const float4 ev = *(const float4*)&einv[wave * 8 + (quad & 1) * 4];
  float* pob = out + (size_t)(b * 64 + o) * TT + 32 * n0 + wave * 8 + (quad & 1) * 4;
  float hiPrev[4] = {0.f, 0.f, 0.f, 0.f};
#pragma unroll
  for (int nt = 0; nt < 5; ++nt) {
    const int fl = nt * 16 + n;
    if (nt < 4 || n == 0) {                  // rank-1 cf=64 term (fl <= 64)
      const float yv = b2f(y64[fl]);
#pragma unroll
      for (int r = 0; r < 4; ++r) acc[nt][r] = fmaf(yv, a64v[r], acc[nt][r]);
    }
    float cur[4];
#pragma unroll
    for (int r = 0; r < 4; ++r)
      cur[r] = __int_as_float(
          __builtin_amdgcn_ds_bpermute(srcl, __float_as_int(acc[nt][r])));
    if (quad < 2) {
      const bool valid = (nt < 4) ? (fl > 0) : (n == 0);
      if (valid) {
        float v[4];
#pragma unroll
        for (int r = 0; r < 4; ++r)
          v[r] = (acc[nt][r] + ((n == 0) ? hiPrev[r] : cur[r])) * ev[r];
        *(float4*)(pob + (fl - 1) * 32) = make_float4(v[0], v[1], v[2], v[3]);
      }
    }
#pragma unroll
    for (int r = 0; r < 4; ++r) hiPrev[r] = cur[r];
  }
}

// ---------------------------------------------------------------------------
extern "C" void kernel_launch(void* const* d_in, const int* in_sizes, int n_in,
                              void* d_out, int out_size, void* d_ws, size_t ws_size,
                              hipStream_t stream) {
  const float* x  = (const float*)d_in[0];   // [8,64,16384]
  const float* wt = (const float*)d_in[1];   // [64,64,33]
  float* out = (float*)d_out;                // [8,64,16384]
  u16* U = (u16*)d_ws;                                        // 35.1 MB bf16
  u16* t16 = (u16*)((char*)d_ws + (size_t)66 * 64 * BNP * 2); // bf16 tables
  float* tf = (float*)(t16 + TAB_TOT);                        // fp32 tables

  dim3 blk(256);
  k0_tables<<<dim3(35),       blk, 0, stream>>>(wt, t16, tf);
  k1_stft  <<<dim3(9, 64, 4), blk, 0, stream>>>(x, t16, U);   // 2 batches/block
  k2_mix   <<<dim3(65, 33),   blk, 0, stream>>>(t16, U);
  k3_istft <<<dim3(8, 64, 8), blk, 0, stream>>>(U, t16, tf, out);
}